// Round 1
// baseline (356.624 us; speedup 1.0000x reference)
//
#include <hip/hip_runtime.h>
#include <hip/hip_bf16.h>

typedef __attribute__((ext_vector_type(8))) short  short8;
typedef __attribute__((ext_vector_type(4))) float  floatx4;

#define TM   64      // rows of B per workgroup
#define UH   2048    // U * H = U * I (row stride of inputs/hidden/out in floats)
#define XPAD 264     // 256 + 8 bf16 pad (16B) to break LDS bank aliasing

// ---------------- prep kernels (run every launch; d_ws is re-poisoned) -------

// Wc[u][g][k]: g in [0,384), k in [0,256): k<128 -> w_ih[u][g][k], else w_hh[u][g][k-128]
__global__ __launch_bounds__(256) void prep_w(const float* __restrict__ w_ih,
                                              const float* __restrict__ w_hh,
                                              __hip_bfloat16* __restrict__ Wc) {
    int idx = blockIdx.x * 256 + threadIdx.x;   // float4 index in [0, 16*384*64)
    int row = idx >> 6;                         // u*384 + g
    int k   = (idx & 63) * 4;
    const float* src = (k < 128) ? (w_ih + (size_t)row * 128 + k)
                                 : (w_hh + (size_t)row * 128 + (k - 128));
    float4 v = *(const float4*)src;
    __hip_bfloat16* d = Wc + (size_t)row * 256 + k;
    d[0] = __float2bfloat16(v.x);
    d[1] = __float2bfloat16(v.y);
    d[2] = __float2bfloat16(v.z);
    d[3] = __float2bfloat16(v.w);
}

// bias_c[u][512]: [0,256): b_ih+b_hh (r,z); [256,384): b_ih n-part; [384,512): b_hh n-part
__global__ __launch_bounds__(256) void prep_bias(const float* __restrict__ b_ih,
                                                 const float* __restrict__ b_hh,
                                                 float* __restrict__ bias_c) {
    int idx = blockIdx.x * 256 + threadIdx.x;   // [0, 16*512)
    int u = idx >> 9;
    int g = idx & 511;
    float v;
    if (g < 256)       v = b_ih[u * 384 + g] + b_hh[u * 384 + g];
    else if (g < 384)  v = b_ih[u * 384 + g];          // xn bias, gate g
    else               v = b_hh[u * 384 + (g - 128)];  // hn bias, gate g-128
    bias_c[idx] = v;
}

// ---------------- fused GRU kernel ------------------------------------------

__global__ __launch_bounds__(256, 2) void gru_fused(
    const float* __restrict__ inputs, const float* __restrict__ hidden,
    const __hip_bfloat16* __restrict__ Wc, const float* __restrict__ bias_c,
    float* __restrict__ out)
{
    __shared__ __align__(16) __hip_bfloat16 Xs[TM][XPAD];
    __shared__ float bs[512];

    const int bx  = blockIdx.x;
    const int mt  = bx & 127;     // 128 m-tiles of 64 rows
    const int u   = bx >> 7;      // 16 u-slices
    const int b0  = mt * TM;
    const int tid = threadIdx.x;

    // stage biases for this u
    bs[tid]       = bias_c[u * 512 + tid];
    bs[tid + 256] = bias_c[u * 512 + tid + 256];

    // stage X = [inputs | hidden] tile (64 rows x 256 cols) fp32 -> bf16 LDS
    const float* xbase = inputs + (size_t)b0 * UH + u * 128;
    const float* hbase = hidden + (size_t)b0 * UH + u * 128;
    #pragma unroll
    for (int i = 0; i < 16; ++i) {
        int f   = i * 256 + tid;       // float4 index in [0, 4096)
        int row = f >> 6;              // 64 float4 per row
        int c4  = f & 63;
        int col = c4 * 4;
        const float* src = (col < 128) ? (xbase + (size_t)row * UH + col)
                                       : (hbase + (size_t)row * UH + (col - 128));
        float4 v = *(const float4*)src;
        __hip_bfloat16* d = &Xs[row][col];
        d[0] = __float2bfloat16(v.x);
        d[1] = __float2bfloat16(v.y);
        d[2] = __float2bfloat16(v.z);
        d[3] = __float2bfloat16(v.w);
    }
    __syncthreads();

    const int lane = tid & 63;
    const int wv   = tid >> 6;     // wave id: owns rows [16*wv, 16*wv+16)
    const int lr   = lane & 15;
    const int lq   = lane >> 4;    // quad

    // A fragments: all 8 k-steps for this wave's 16 rows
    // layout: A[m = lane&15][k = quad*8 + j]
    short8 aF[8];
    const short* xrow = (const short*)&Xs[wv * 16 + lr][0];
    #pragma unroll
    for (int s = 0; s < 8; ++s)
        aF[s] = *(const short8*)(xrow + s * 32 + lq * 8);

    // accumulators: [0,16) = r,z tiles (K=256); [16,24) = xn (K=128 lo); [24,32) = hn (K=128 hi)
    floatx4 acc[32];
    #pragma unroll
    for (int t = 0; t < 32; ++t) acc[t] = (floatx4){0.f, 0.f, 0.f, 0.f};

    const short* Wg = (const short*)(Wc + (size_t)u * 384 * 256);

    // r,z gates: gates [0,256), full K=256 concat
    #pragma unroll
    for (int t = 0; t < 16; ++t) {
        const short* brow = Wg + (size_t)(t * 16 + lr) * 256 + lq * 8;
        #pragma unroll
        for (int s = 0; s < 8; ++s) {
            short8 bF = *(const short8*)(brow + s * 32);
            acc[t] = __builtin_amdgcn_mfma_f32_16x16x32_bf16(aF[s], bF, acc[t], 0, 0, 0);
        }
    }
    // n gate: gates [256,384). cols [0,128) of Wc row = w_ih (pairs with x half of A),
    //         cols [128,256) = w_hh (pairs with h half of A). Separate accumulators.
    #pragma unroll
    for (int t = 0; t < 8; ++t) {
        const short* brow = Wg + (size_t)(256 + t * 16 + lr) * 256 + lq * 8;
        #pragma unroll
        for (int s = 0; s < 4; ++s) {
            short8 bF = *(const short8*)(brow + s * 32);
            acc[16 + t] = __builtin_amdgcn_mfma_f32_16x16x32_bf16(aF[s], bF, acc[16 + t], 0, 0, 0);
        }
        #pragma unroll
        for (int s = 4; s < 8; ++s) {
            short8 bF = *(const short8*)(brow + s * 32);
            acc[24 + t] = __builtin_amdgcn_mfma_f32_16x16x32_bf16(aF[s], bF, acc[24 + t], 0, 0, 0);
        }
    }

    // epilogue: C/D layout col = lane&15, row = quad*4 + reg
    const int mloc = wv * 16 + lq * 4;
    #pragma unroll
    for (int t = 0; t < 8; ++t) {
        int c = t * 16 + lr;               // h-column in [0,128)
        float br  = bs[c];
        float bz  = bs[128 + c];
        float bxn = bs[256 + c];
        float bhn = bs[384 + c];
        #pragma unroll
        for (int r = 0; r < 4; ++r) {
            int m = mloc + r;
            float rv = 1.f / (1.f + __expf(-(acc[t][r] + br)));
            float zv = 1.f / (1.f + __expf(-(acc[8 + t][r] + bz)));
            float npre = (acc[16 + t][r] + bxn) + rv * (acc[24 + t][r] + bhn);
            float e  = __expf(2.f * npre);
            float nv = 1.f - 2.f / (e + 1.f);             // tanh(npre)
            float hv = __bfloat162float(Xs[m][128 + c]);  // original hidden (bf16)
            out[(size_t)(b0 + m) * UH + u * 128 + c] = (1.f - zv) * nv + zv * hv;
        }
    }
}

// ---------------- launch -----------------------------------------------------

extern "C" void kernel_launch(void* const* d_in, const int* in_sizes, int n_in,
                              void* d_out, int out_size, void* d_ws, size_t ws_size,
                              hipStream_t stream) {
    const float* inputs = (const float*)d_in[0];
    const float* hidden = (const float*)d_in[1];
    const float* w_ih   = (const float*)d_in[2];
    const float* w_hh   = (const float*)d_in[3];
    const float* b_ih   = (const float*)d_in[4];
    const float* b_hh   = (const float*)d_in[5];
    float* out = (float*)d_out;

    __hip_bfloat16* Wc = (__hip_bfloat16*)d_ws;
    float* bias_c = (float*)((char*)d_ws + (size_t)16 * 384 * 256 * 2);  // +3,145,728 B

    // 16*384*64 float4 conversions = 393216 threads
    prep_w<<<dim3(1536), dim3(256), 0, stream>>>(w_ih, w_hh, Wc);
    prep_bias<<<dim3(32), dim3(256), 0, stream>>>(b_ih, b_hh, bias_c);
    // 128 m-tiles x 16 u
    gru_fused<<<dim3(2048), dim3(256), 0, stream>>>(inputs, hidden, Wc, bias_c, out);
}

// Round 2
// 233.091 us; speedup vs baseline: 1.5300x; 1.5300x over previous
//
#include <hip/hip_runtime.h>
#include <hip/hip_bf16.h>

typedef __attribute__((ext_vector_type(8))) short  short8;
typedef __attribute__((ext_vector_type(4))) float  floatx4;

#define TM   64      // rows of B per workgroup
#define UH   2048    // U * H (row stride of inputs/hidden/out in floats)
#define XPAD 264     // 256 + 8 bf16 pad (528 B row stride, 16B aligned)

#define MFMA16(a,b,c) __builtin_amdgcn_mfma_f32_16x16x32_bf16(a, b, c, 0, 0, 0)

// ---------------- prep kernel (runs every launch; d_ws is re-poisoned) -------
// blocks [0,1536): Wc[u][g][k], k<128 -> w_ih, k>=128 -> w_hh  (bf16)
// blocks [1536,1568): bias_c[u][512]
__global__ __launch_bounds__(256) void prep(const float* __restrict__ w_ih,
                                            const float* __restrict__ w_hh,
                                            const float* __restrict__ b_ih,
                                            const float* __restrict__ b_hh,
                                            __hip_bfloat16* __restrict__ Wc,
                                            float* __restrict__ bias_c) {
    if (blockIdx.x < 1536) {
        int idx = blockIdx.x * 256 + threadIdx.x;   // float4 index in [0, 16*384*64)
        int row = idx >> 6;                         // u*384 + g
        int k   = (idx & 63) * 4;
        const float* src = (k < 128) ? (w_ih + (size_t)row * 128 + k)
                                     : (w_hh + (size_t)row * 128 + (k - 128));
        float4 v = *(const float4*)src;
        __hip_bfloat16* d = Wc + (size_t)row * 256 + k;
        d[0] = __float2bfloat16(v.x);
        d[1] = __float2bfloat16(v.y);
        d[2] = __float2bfloat16(v.z);
        d[3] = __float2bfloat16(v.w);
    } else {
        int idx = (blockIdx.x - 1536) * 256 + threadIdx.x;   // [0, 16*512)
        int u = idx >> 9;
        int g = idx & 511;
        float v;
        if (g < 256)       v = b_ih[u * 384 + g] + b_hh[u * 384 + g];
        else if (g < 384)  v = b_ih[u * 384 + g];          // xn bias
        else               v = b_hh[u * 384 + (g - 128)];  // hn bias
        bias_c[idx] = v;
    }
}

// ---------------- fused GRU kernel ------------------------------------------
// Workgroup: 64 rows x one u. Waves split the 128 output columns (32 each);
// each B-fragment is loaded once per wave and reused across 4 m-tiles.
__global__ __launch_bounds__(256, 2) void gru_fused(
    const float* __restrict__ inputs, const float* __restrict__ hidden,
    const __hip_bfloat16* __restrict__ Wc, const float* __restrict__ bias_c,
    float* __restrict__ out)
{
    __shared__ __align__(16) __hip_bfloat16 Xs[TM][XPAD];
    __shared__ float bs[512];

    const int bx  = blockIdx.x;
    const int mt  = bx & 127;     // 128 m-tiles of 64 rows
    const int u   = bx >> 7;      // 16 u-slices
    const int b0  = mt * TM;
    const int tid = threadIdx.x;

    // stage biases for this u
    bs[tid]       = bias_c[u * 512 + tid];
    bs[tid + 256] = bias_c[u * 512 + tid + 256];

    // stage X = [inputs | hidden] tile (64 rows x 256 cols) fp32 -> bf16 LDS
    const float* xbase = inputs + (size_t)b0 * UH + u * 128;
    const float* hbase = hidden + (size_t)b0 * UH + u * 128;
    #pragma unroll
    for (int i = 0; i < 16; ++i) {
        int f   = i * 256 + tid;       // float4 index in [0, 4096)
        int row = f >> 6;              // 64 float4 per row
        int col = (f & 63) * 4;
        const float* src = (col < 128) ? (xbase + (size_t)row * UH + col)
                                       : (hbase + (size_t)row * UH + (col - 128));
        float4 v = *(const float4*)src;
        __hip_bfloat16* d = &Xs[row][col];
        d[0] = __float2bfloat16(v.x);
        d[1] = __float2bfloat16(v.y);
        d[2] = __float2bfloat16(v.z);
        d[3] = __float2bfloat16(v.w);
    }
    __syncthreads();

    const int lane = tid & 63;
    const int wv   = tid >> 6;     // wave id: owns output cols [32*wv, 32*wv+32)
    const int lr   = lane & 15;
    const int lq   = lane >> 4;    // quad

    // acc[ct][cat][m4]: ct = col-subtile (16 cols), cat 0=r 1=z 2=xn 3=hn,
    // m4 = m-tile (16 rows). 32 floatx4 = 128 accumulator floats.
    floatx4 acc[2][4][4];
    #pragma unroll
    for (int ct = 0; ct < 2; ++ct)
        #pragma unroll
        for (int cat = 0; cat < 4; ++cat)
            #pragma unroll
            for (int m4 = 0; m4 < 4; ++m4)
                acc[ct][cat][m4] = (floatx4){0.f, 0.f, 0.f, 0.f};

    const short* Wg = (const short*)(Wc + (size_t)u * 384 * 256);
    const int koff = lq * 8;       // A/B fragment k-offset: k = quad*8 + j

    #pragma unroll
    for (int s = 0; s < 8; ++s) {
        // A fragments for all 4 m-tiles at this k-step (LDS)
        short8 aF[4];
        #pragma unroll
        for (int m4 = 0; m4 < 4; ++m4)
            aF[m4] = *(const short8*)((const short*)&Xs[m4 * 16 + lr][0] + s * 32 + koff);

        #pragma unroll
        for (int ct = 0; ct < 2; ++ct) {
            const int gc = wv * 32 + ct * 16 + lr;   // gate/col row in W
            const short* base = Wg + (size_t)gc * 256 + s * 32 + koff;
            short8 bR = *(const short8*)(base);                 // r: gate gc
            short8 bZ = *(const short8*)(base + 128 * 256);     // z: gate 128+gc
            short8 bN = *(const short8*)(base + 256 * 256);     // n: gate 256+gc
            #pragma unroll
            for (int m4 = 0; m4 < 4; ++m4) {
                acc[ct][0][m4] = MFMA16(aF[m4], bR, acc[ct][0][m4]);
                acc[ct][1][m4] = MFMA16(aF[m4], bZ, acc[ct][1][m4]);
                if (s < 4) acc[ct][2][m4] = MFMA16(aF[m4], bN, acc[ct][2][m4]);
                else       acc[ct][3][m4] = MFMA16(aF[m4], bN, acc[ct][3][m4]);
            }
        }
    }

    // epilogue: C/D layout col = lane&15, row = quad*4 + reg
    #pragma unroll
    for (int ct = 0; ct < 2; ++ct) {
        const int c = wv * 32 + ct * 16 + lr;        // output column in [0,128)
        const float br  = bs[c];
        const float bz  = bs[128 + c];
        const float bxn = bs[256 + c];
        const float bhn = bs[384 + c];
        #pragma unroll
        for (int m4 = 0; m4 < 4; ++m4) {
            #pragma unroll
            for (int r = 0; r < 4; ++r) {
                const int m = m4 * 16 + lq * 4 + r;
                float rv = 1.f / (1.f + __expf(-(acc[ct][0][m4][r] + br)));
                float zv = 1.f / (1.f + __expf(-(acc[ct][1][m4][r] + bz)));
                float npre = (acc[ct][2][m4][r] + bxn) + rv * (acc[ct][3][m4][r] + bhn);
                float e  = __expf(2.f * npre);
                float nv = 1.f - 2.f / (e + 1.f);             // tanh(npre)
                float hv = __bfloat162float(Xs[m][128 + c]);  // original hidden (bf16)
                out[(size_t)(b0 + m) * UH + u * 128 + c] = (1.f - zv) * nv + zv * hv;
            }
        }
    }
}

// ---------------- launch -----------------------------------------------------

extern "C" void kernel_launch(void* const* d_in, const int* in_sizes, int n_in,
                              void* d_out, int out_size, void* d_ws, size_t ws_size,
                              hipStream_t stream) {
    const float* inputs = (const float*)d_in[0];
    const float* hidden = (const float*)d_in[1];
    const float* w_ih   = (const float*)d_in[2];
    const float* w_hh   = (const float*)d_in[3];
    const float* b_ih   = (const float*)d_in[4];
    const float* b_hh   = (const float*)d_in[5];
    float* out = (float*)d_out;

    __hip_bfloat16* Wc = (__hip_bfloat16*)d_ws;
    float* bias_c = (float*)((char*)d_ws + (size_t)16 * 384 * 256 * 2);  // +3,145,728 B

    prep<<<dim3(1568), dim3(256), 0, stream>>>(w_ih, w_hh, b_ih, b_hh, Wc, bias_c);
    gru_fused<<<dim3(2048), dim3(256), 0, stream>>>(inputs, hidden, Wc, bias_c, out);
}

// Round 3
// 204.859 us; speedup vs baseline: 1.7408x; 1.1378x over previous
//
#include <hip/hip_runtime.h>
#include <hip/hip_bf16.h>

typedef __attribute__((ext_vector_type(8))) short  short8;
typedef __attribute__((ext_vector_type(4))) float  floatx4;

#define UH   2048    // U * H (row stride of inputs/hidden/out in floats)
#define XPAD 264     // 256 + 8 bf16 pad

#define MFMA16(a,b,c) __builtin_amdgcn_mfma_f32_16x16x32_bf16(a, b, c, 0, 0, 0)

// ---------------- prep kernel -------------------------------------------------
// blocks [0,768): Wc in MFMA-fragment order.
//   fragment id = (u*24 + gt)*8 + s   (gt = gate-tile of 16 gates, s = k-step)
//   within fragment: lane*8 shorts; element j = W[u][gt*16+(lane&15)][s*32+(lane>>4)*8+j]
//   (k<128 -> w_ih, k>=128 -> w_hh)
// blocks [768,800): bias_c[u][512]: [0,256)=b_ih+b_hh (r,z); [256,384)=b_ih n; [384,512)=b_hh n
__global__ __launch_bounds__(256) void prep(const float* __restrict__ w_ih,
                                            const float* __restrict__ w_hh,
                                            const float* __restrict__ b_ih,
                                            const float* __restrict__ b_hh,
                                            __hip_bfloat16* __restrict__ Wc,
                                            float* __restrict__ bias_c) {
    if (blockIdx.x < 768) {
        int t   = blockIdx.x * 256 + threadIdx.x;   // [0, 196608) 8-elem chunks
        int u   = t / 12288;                        // 24*8*64 chunks per u
        int rem = t - u * 12288;
        int gt   = rem >> 9;                        // [0,24)
        int s    = (rem >> 6) & 7;                  // [0,8)
        int lane = rem & 63;
        int g = gt * 16 + (lane & 15);
        int k = s * 32 + (lane >> 4) * 8;
        int row = u * 384 + g;
        const float* src = (k < 128) ? (w_ih + (size_t)row * 128 + k)
                                     : (w_hh + (size_t)row * 128 + (k - 128));
        float4 v0 = ((const float4*)src)[0];
        float4 v1 = ((const float4*)src)[1];
        __hip_bfloat16* d = Wc + (size_t)t * 8;
        d[0] = __float2bfloat16(v0.x);  d[1] = __float2bfloat16(v0.y);
        d[2] = __float2bfloat16(v0.z);  d[3] = __float2bfloat16(v0.w);
        d[4] = __float2bfloat16(v1.x);  d[5] = __float2bfloat16(v1.y);
        d[6] = __float2bfloat16(v1.z);  d[7] = __float2bfloat16(v1.w);
    } else {
        int idx = (blockIdx.x - 768) * 256 + threadIdx.x;   // [0, 8192)
        int u = idx >> 9;
        int g = idx & 511;
        float v;
        if (g < 256)       v = b_ih[u * 384 + g] + b_hh[u * 384 + g];
        else if (g < 384)  v = b_ih[u * 384 + g];
        else               v = b_hh[u * 384 + (g - 128)];
        bias_c[idx] = v;
    }
}

// ---------------- fused GRU kernel --------------------------------------------
// Block: 64 rows x one u, 512 threads (8 waves). Wave wv owns output cols
// [16*wv, 16*wv+16); B-fragments are contiguous 1KB coalesced loads, each
// reused across 4 m-tiles. acc = 64 VGPRs/lane.
__global__ __launch_bounds__(512, 3) void gru_fused(
    const float* __restrict__ inputs, const float* __restrict__ hidden,
    const __hip_bfloat16* __restrict__ Wc, const float* __restrict__ bias_c,
    float* __restrict__ out)
{
    __shared__ __align__(16) __hip_bfloat16 Xs[64][XPAD];
    __shared__ float bs[512];

    const int bx  = blockIdx.x;
    const int mt  = bx & 127;     // 128 m-tiles of 64 rows
    const int u   = bx >> 7;      // 16 u-slices
    const int b0  = mt * 64;
    const int tid = threadIdx.x;

    bs[tid] = bias_c[u * 512 + tid];

    // stage X = [inputs | hidden] (64 rows x 256 cols) fp32 -> bf16 LDS
    const float* xbase = inputs + (size_t)b0 * UH + u * 128;
    const float* hbase = hidden + (size_t)b0 * UH + u * 128;
    #pragma unroll
    for (int i = 0; i < 8; ++i) {
        int f   = i * 512 + tid;       // float4 index in [0, 4096)
        int row = f >> 6;
        int col = (f & 63) * 4;
        const float* src = (col < 128) ? (xbase + (size_t)row * UH + col)
                                       : (hbase + (size_t)row * UH + (col - 128));
        float4 v = *(const float4*)src;
        __hip_bfloat16* d = &Xs[row][col];
        d[0] = __float2bfloat16(v.x);
        d[1] = __float2bfloat16(v.y);
        d[2] = __float2bfloat16(v.z);
        d[3] = __float2bfloat16(v.w);
    }
    __syncthreads();

    const int lane = tid & 63;
    const int wv   = tid >> 6;     // [0,8): owns cols [16*wv, 16*wv+16)
    const int lr   = lane & 15;
    const int lq   = lane >> 4;

    floatx4 aR[4], aZ[4], aXN[4], aHN[4];
    #pragma unroll
    for (int m4 = 0; m4 < 4; ++m4) {
        aR[m4]  = (floatx4){0.f, 0.f, 0.f, 0.f};
        aZ[m4]  = (floatx4){0.f, 0.f, 0.f, 0.f};
        aXN[m4] = (floatx4){0.f, 0.f, 0.f, 0.f};
        aHN[m4] = (floatx4){0.f, 0.f, 0.f, 0.f};
    }

    // fragment base for this u + this lane's 16B slot
    const short* WgU = (const short*)Wc + (size_t)u * 98304 + lane * 8;
    // gate-tiles: r -> wv, z -> 8+wv, n -> 16+wv; fragment offset = (gt*8+s)*512 shorts

    #pragma unroll
    for (int s = 0; s < 8; ++s) {
        short8 aF[4];
        #pragma unroll
        for (int m4 = 0; m4 < 4; ++m4)
            aF[m4] = *(const short8*)((const short*)&Xs[m4 * 16 + lr][0] + s * 32 + lq * 8);

        short8 bR = *(const short8*)(WgU + (size_t)(wv * 8 + s) * 512);
        short8 bZ = *(const short8*)(WgU + (size_t)(64 + wv * 8 + s) * 512);
        short8 bN = *(const short8*)(WgU + (size_t)(128 + wv * 8 + s) * 512);

        #pragma unroll
        for (int m4 = 0; m4 < 4; ++m4) {
            aR[m4] = MFMA16(aF[m4], bR, aR[m4]);
            aZ[m4] = MFMA16(aF[m4], bZ, aZ[m4]);
            if (s < 4) aXN[m4] = MFMA16(aF[m4], bN, aXN[m4]);
            else       aHN[m4] = MFMA16(aF[m4], bN, aHN[m4]);
        }
    }

    // epilogue: C/D layout col = lane&15, row = quad*4 + reg
    const int c = wv * 16 + lr;            // output column in [0,128)
    const float br  = bs[c];
    const float bz  = bs[128 + c];
    const float bxn = bs[256 + c];
    const float bhn = bs[384 + c];
    float* obase = out + (size_t)b0 * UH + u * 128 + c;

    #pragma unroll
    for (int m4 = 0; m4 < 4; ++m4) {
        #pragma unroll
        for (int r = 0; r < 4; ++r) {
            const int m = m4 * 16 + lq * 4 + r;
            float rv = __builtin_amdgcn_rcpf(1.f + __expf(-(aR[m4][r] + br)));
            float zv = __builtin_amdgcn_rcpf(1.f + __expf(-(aZ[m4][r] + bz)));
            float npre = (aXN[m4][r] + bxn) + rv * (aHN[m4][r] + bhn);
            float nv = 2.f * __builtin_amdgcn_rcpf(1.f + __expf(-2.f * npre)) - 1.f;  // tanh
            float hv = __bfloat162float(Xs[m][128 + c]);   // original hidden (bf16)
            obase[(size_t)m * UH] = nv + zv * (hv - nv);
        }
    }
}

// ---------------- launch ------------------------------------------------------

extern "C" void kernel_launch(void* const* d_in, const int* in_sizes, int n_in,
                              void* d_out, int out_size, void* d_ws, size_t ws_size,
                              hipStream_t stream) {
    const float* inputs = (const float*)d_in[0];
    const float* hidden = (const float*)d_in[1];
    const float* w_ih   = (const float*)d_in[2];
    const float* w_hh   = (const float*)d_in[3];
    const float* b_ih   = (const float*)d_in[4];
    const float* b_hh   = (const float*)d_in[5];
    float* out = (float*)d_out;

    __hip_bfloat16* Wc = (__hip_bfloat16*)d_ws;
    float* bias_c = (float*)((char*)d_ws + (size_t)16 * 384 * 256 * 2);  // +3,145,728 B

    prep<<<dim3(800), dim3(256), 0, stream>>>(w_ih, w_hh, b_ih, b_hh, Wc, bias_c);
    gru_fused<<<dim3(2048), dim3(512), 0, stream>>>(inputs, hidden, Wc, bias_c, out);
}

// Round 4
// 199.954 us; speedup vs baseline: 1.7835x; 1.0245x over previous
//
#include <hip/hip_runtime.h>
#include <hip/hip_bf16.h>

typedef __attribute__((ext_vector_type(8))) short  short8;
typedef __attribute__((ext_vector_type(4))) float  floatx4;

#define UH   2048    // U * H (row stride of inputs/hidden/out in floats)
#define XPAD 264     // 256 + 8 bf16 pad (528 B row stride, 16B aligned)

#define MFMA16(a,b,c) __builtin_amdgcn_mfma_f32_16x16x32_bf16(a, b, c, 0, 0, 0)

static __device__ __forceinline__ unsigned int pkbf16(float a, float b) {
    __hip_bfloat162 p = __float22bfloat162_rn(make_float2(a, b));
    return *(unsigned int*)&p;
}

// ---------------- prep kernel -------------------------------------------------
// Wc in MFMA-fragment order: fragment id = (u*24 + gt)*8 + s  (gt = 16-gate tile,
// s = k-step). Element lane*8+j = W[u][gt*16+(lane&15)][s*32+(lane>>4)*8+j],
// k<128 -> w_ih, else w_hh. Thread = one 8-float k-chunk: coalesced 32B reads,
// one 16B packed store.
// blocks [0,768): weights; [768,800): bias_c[u][512]
__global__ __launch_bounds__(256) void prep(const float* __restrict__ w_ih,
                                            const float* __restrict__ w_hh,
                                            const float* __restrict__ b_ih,
                                            const float* __restrict__ b_hh,
                                            __hip_bfloat16* __restrict__ Wc,
                                            float* __restrict__ bias_c) {
    if (blockIdx.x < 768) {
        int t   = blockIdx.x * 256 + threadIdx.x;   // [0, 196608)
        int k8  = t & 31;                           // 8-float chunk within row
        int row = t >> 5;                           // u*384 + g
        int u   = row / 384;
        int g   = row - u * 384;
        int k   = k8 * 8;
        const float* src = (k < 128) ? (w_ih + (size_t)row * 128 + k)
                                     : (w_hh + (size_t)row * 128 + (k - 128));
        float4 v0 = ((const float4*)src)[0];
        float4 v1 = ((const float4*)src)[1];
        uint4 w;
        w.x = pkbf16(v0.x, v0.y);
        w.y = pkbf16(v0.z, v0.w);
        w.z = pkbf16(v1.x, v1.y);
        w.w = pkbf16(v1.z, v1.w);
        int gt = g >> 4, lr = g & 15;
        int s  = k8 >> 2, lq = k8 & 3;
        size_t off = (size_t)((u * 24 + gt) * 8 + s) * 512 + (lq * 16 + lr) * 8;
        *(uint4*)(Wc + off) = w;
    } else {
        int idx = (blockIdx.x - 768) * 256 + threadIdx.x;   // [0, 8192)
        int u = idx >> 9;
        int g = idx & 511;
        float v;
        if (g < 256)       v = b_ih[u * 384 + g] + b_hh[u * 384 + g];
        else if (g < 384)  v = b_ih[u * 384 + g];          // xn bias
        else               v = b_hh[u * 384 + (g - 128)];  // hn bias
        bias_c[idx] = v;
    }
}

// ---------------- fused GRU kernel --------------------------------------------
// Block: 64 rows x one u, 512 threads (8 waves). Wave wv owns output cols
// [16*wv, 16*wv+16); B-fragments are contiguous 1KB coalesced loads reused
// across 4 m-tiles. XCD-aware swizzle: XCD x (bx&7) handles u in {2x, 2x+1}
// -> 768 KB Wc working set per XCD, L2-resident.
__global__ __launch_bounds__(512, 3) void gru_fused(
    const float* __restrict__ inputs, const float* __restrict__ hidden,
    const __hip_bfloat16* __restrict__ Wc, const float* __restrict__ bias_c,
    float* __restrict__ out)
{
    __shared__ __align__(16) __hip_bfloat16 Xs[64][XPAD];
    __shared__ float bs[512];

    const int bx  = blockIdx.x;
    const int u   = ((bx & 7) << 1) | ((bx >> 3) & 1);  // XCD-local u pair
    const int mt  = bx >> 4;                            // [0,128)
    const int b0  = mt * 64;
    const int tid = threadIdx.x;

    bs[tid] = bias_c[u * 512 + tid];

    // stage X = [inputs | hidden] (64 rows x 256 cols) fp32 -> bf16 LDS
    const float* xbase = inputs + (size_t)b0 * UH + u * 128;
    const float* hbase = hidden + (size_t)b0 * UH + u * 128;
    #pragma unroll
    for (int i = 0; i < 8; ++i) {
        int f   = i * 512 + tid;       // float4 index in [0, 4096)
        int row = f >> 6;
        int col = (f & 63) * 4;
        const float* src = (col < 128) ? (xbase + (size_t)row * UH + col)
                                       : (hbase + (size_t)row * UH + (col - 128));
        float4 v = *(const float4*)src;
        uint2 w;
        w.x = pkbf16(v.x, v.y);
        w.y = pkbf16(v.z, v.w);
        *(uint2*)&Xs[row][col] = w;
    }
    __syncthreads();

    const int lane = tid & 63;
    const int wv   = tid >> 6;     // [0,8): owns cols [16*wv, 16*wv+16)
    const int lr   = lane & 15;
    const int lq   = lane >> 4;

    floatx4 aR[4], aZ[4], aXN[4], aHN[4];
    #pragma unroll
    for (int m4 = 0; m4 < 4; ++m4) {
        aR[m4]  = (floatx4){0.f, 0.f, 0.f, 0.f};
        aZ[m4]  = (floatx4){0.f, 0.f, 0.f, 0.f};
        aXN[m4] = (floatx4){0.f, 0.f, 0.f, 0.f};
        aHN[m4] = (floatx4){0.f, 0.f, 0.f, 0.f};
    }

    // fragment base for this u + this lane's 16B slot
    const short* WgU = (const short*)Wc + (size_t)u * 98304 + lane * 8;
    // gate-tiles: r -> wv, z -> 8+wv, n -> 16+wv; fragment = (gt*8+s)*512 shorts

    #pragma unroll
    for (int s = 0; s < 8; ++s) {
        short8 aF[4];
        #pragma unroll
        for (int m4 = 0; m4 < 4; ++m4)
            aF[m4] = *(const short8*)((const short*)&Xs[m4 * 16 + lr][0] + s * 32 + lq * 8);

        short8 bR = *(const short8*)(WgU + (size_t)(wv * 8 + s) * 512);
        short8 bZ = *(const short8*)(WgU + (size_t)(64 + wv * 8 + s) * 512);
        short8 bN = *(const short8*)(WgU + (size_t)(128 + wv * 8 + s) * 512);

        #pragma unroll
        for (int m4 = 0; m4 < 4; ++m4) {
            aR[m4] = MFMA16(aF[m4], bR, aR[m4]);
            aZ[m4] = MFMA16(aF[m4], bZ, aZ[m4]);
            if (s < 4) aXN[m4] = MFMA16(aF[m4], bN, aXN[m4]);
            else       aHN[m4] = MFMA16(aF[m4], bN, aHN[m4]);
        }
    }

    // epilogue: C/D layout col = lane&15, row = quad*4 + reg
    const int c = wv * 16 + lr;            // output column in [0,128)
    const float br  = bs[c];
    const float bz  = bs[128 + c];
    const float bxn = bs[256 + c];
    const float bhn = bs[384 + c];
    float* obase = out + (size_t)b0 * UH + u * 128 + c;

    #pragma unroll
    for (int m4 = 0; m4 < 4; ++m4) {
        #pragma unroll
        for (int r = 0; r < 4; ++r) {
            const int m = m4 * 16 + lq * 4 + r;
            float rv = __builtin_amdgcn_rcpf(1.f + __expf(-(aR[m4][r] + br)));
            float zv = __builtin_amdgcn_rcpf(1.f + __expf(-(aZ[m4][r] + bz)));
            float npre = (aXN[m4][r] + bxn) + rv * (aHN[m4][r] + bhn);
            float nv = 2.f * __builtin_amdgcn_rcpf(1.f + __expf(-2.f * npre)) - 1.f;  // tanh
            float hv = __bfloat162float(Xs[m][128 + c]);   // original hidden (bf16)
            obase[(size_t)m * UH] = nv + zv * (hv - nv);
        }
    }
}

// ---------------- launch ------------------------------------------------------

extern "C" void kernel_launch(void* const* d_in, const int* in_sizes, int n_in,
                              void* d_out, int out_size, void* d_ws, size_t ws_size,
                              hipStream_t stream) {
    const float* inputs = (const float*)d_in[0];
    const float* hidden = (const float*)d_in[1];
    const float* w_ih   = (const float*)d_in[2];
    const float* w_hh   = (const float*)d_in[3];
    const float* b_ih   = (const float*)d_in[4];
    const float* b_hh   = (const float*)d_in[5];
    float* out = (float*)d_out;

    __hip_bfloat16* Wc = (__hip_bfloat16*)d_ws;
    float* bias_c = (float*)((char*)d_ws + (size_t)16 * 384 * 256 * 2);  // +3,145,728 B

    prep<<<dim3(800), dim3(256), 0, stream>>>(w_ih, w_hh, b_ih, b_hh, Wc, bias_c);
    gru_fused<<<dim3(2048), dim3(512), 0, stream>>>(inputs, hidden, Wc, bias_c, out);
}